// Round 6
// baseline (178.231 us; speedup 1.0000x reference)
//
#include <hip/hip_runtime.h>

#define B_SZ   512
#define VFD    4096
#define HIDD   2048
#define EMBD   300
#define NLAB   2000
#define NPAD   320

#define G1_SPLIT 4          // gemm1 k-chunks: K=4096 -> 1024 each, 1024 blocks
#define G2_SPLIT 8          // gemm2 k-chunks: K=2048 -> 256 each, 320 blocks
#define SD_SPLIT 4          // scores d-quarters: 320 -> 80 dims each

typedef __attribute__((ext_vector_type(8))) short short8x;
typedef __attribute__((ext_vector_type(4))) float f32x4;
typedef __attribute__((ext_vector_type(8))) unsigned short ushort8;
typedef __attribute__((ext_vector_type(4))) unsigned short ushort4x;

typedef const __attribute__((address_space(1))) unsigned int* gas_t;
typedef __attribute__((address_space(3))) unsigned int* las_t;

__device__ inline unsigned short f2bf(float x) {
    unsigned u = __float_as_uint(x);
    u += 0x7FFF + ((u >> 16) & 1);          // round-to-nearest-even
    return (unsigned short)(u >> 16);
}

// ---------------------------------------------------------------------------
// Fused prep (single launch, grid-range dispatch):
//   blocks [0,1024):      Xb = bf16(relu(vfs)), 8 elem/thread
//   blocks [1024,3072):   W1T[n][k] = bf16(W1[k][n])   (transpose-convert)
//   blocks [3072,3232):   W2T[n][k] = bf16(W2[k][n]), n>=300 zero-padded
// ---------------------------------------------------------------------------
__global__ __launch_bounds__(256) void prep_kernel(
    const float* __restrict__ vfs, unsigned short* __restrict__ Xb,
    const float* __restrict__ W1, unsigned short* __restrict__ W1T,
    const float* __restrict__ W2, unsigned short* __restrict__ W2T)
{
    __shared__ float tile[64][65];
    const int tid = threadIdx.x;
    const int blk = blockIdx.x;

    if (blk < 1024) {                       // conv+relu Xb
        const int i = (blk * 256 + tid) * 8;
        float4 a = *(const float4*)&vfs[i];
        float4 b = *(const float4*)&vfs[i + 4];
        ushort8 o;
        o[0] = f2bf(fmaxf(a.x, 0.f)); o[1] = f2bf(fmaxf(a.y, 0.f));
        o[2] = f2bf(fmaxf(a.z, 0.f)); o[3] = f2bf(fmaxf(a.w, 0.f));
        o[4] = f2bf(fmaxf(b.x, 0.f)); o[5] = f2bf(fmaxf(b.y, 0.f));
        o[6] = f2bf(fmaxf(b.z, 0.f)); o[7] = f2bf(fmaxf(b.w, 0.f));
        *(ushort8*)&Xb[i] = o;
        return;
    }

    const float* in; unsigned short* out; int N, ldK, bx, by;
    if (blk < 3072) {                       // W1: K=4096, N=2048, grid (32,64)
        const int b = blk - 1024;
        in = W1; out = W1T; N = HIDD; ldK = VFD; bx = b & 31; by = b >> 5;
    } else {                                // W2: K=2048, N=300->320, grid (5,32)
        const int b = blk - 3072;
        in = W2; out = W2T; N = EMBD; ldK = HIDD; bx = b % 5; by = b / 5;
    }
    const int n0 = bx * 64, k0 = by * 64;

    #pragma unroll
    for (int i = 0; i < 4; ++i) {
        const int s = tid + 256 * i;
        const int kr = s >> 4, nc = (s & 15) * 4;
        float4 v = {0.f, 0.f, 0.f, 0.f};
        if (n0 + nc < N) v = *(const float4*)&in[(size_t)(k0 + kr) * N + n0 + nc];
        tile[kr][nc + 0] = v.x; tile[kr][nc + 1] = v.y;
        tile[kr][nc + 2] = v.z; tile[kr][nc + 3] = v.w;
    }
    __syncthreads();

    const int row = tid >> 2, kq = (tid & 3) * 16;
    ushort8 o0, o1;
    #pragma unroll
    for (int j = 0; j < 8; ++j) o0[j] = f2bf(tile[kq + j][row]);
    #pragma unroll
    for (int j = 0; j < 8; ++j) o1[j] = f2bf(tile[kq + 8 + j][row]);
    const size_t off = (size_t)(n0 + row) * ldK + k0 + kq;
    *(ushort8*)&out[off]     = o0;
    *(ushort8*)&out[off + 8] = o1;
}

// ---------------------------------------------------------------------------
// bf16 MFMA GEMM: Cpart[z][M][LDC] = A[M][LDA] @ Bt[N][LDB]^T over k-chunk z.
// BM=BN=64, BK=32, 4 waves, wave = 32x32 (2x2 mfma 16x16x32).
// Double-buffered LDS + 1-ahead global_load_lds, ONE barrier per iter.
// ---------------------------------------------------------------------------
template<int LDA, int LDB, int LDC, int KCHUNK>
__global__ __launch_bounds__(256) void gemm_bf16_kernel(
    const unsigned short* __restrict__ A,
    const unsigned short* __restrict__ Bt,
    float* __restrict__ Cpart, int M)
{
    __shared__ unsigned short As[2][2048];   // 2 x 4 KB
    __shared__ unsigned short Bs[2][2048];

    const int tid = threadIdx.x;
    const int m0 = blockIdx.y * 64, n0 = blockIdx.x * 64;
    const int kbase = blockIdx.z * KCHUNK;

    const int soct = tid >> 6, srow = tid & 63;
    const unsigned short* ga = A  + (size_t)(m0 + srow) * LDA + kbase + soct * 8;
    const unsigned short* gb = Bt + (size_t)(n0 + srow) * LDB + kbase + soct * 8;

    const int lane = tid & 63;
    const int wave = tid >> 6;
    const int wm = (wave & 1) * 32;
    const int wn = (wave >> 1) * 32;
    const int q = lane >> 4, l15 = lane & 15;

    f32x4 acc00 = {0.f,0.f,0.f,0.f}, acc01 = {0.f,0.f,0.f,0.f};
    f32x4 acc10 = {0.f,0.f,0.f,0.f}, acc11 = {0.f,0.f,0.f,0.f};

    __builtin_amdgcn_global_load_lds((gas_t)(const void*)ga,
                                     (las_t)(void*)&As[0][tid * 8], 16, 0, 0);
    __builtin_amdgcn_global_load_lds((gas_t)(const void*)gb,
                                     (las_t)(void*)&Bs[0][tid * 8], 16, 0, 0);

    const int iters = KCHUNK / 32;
    for (int t = 0; t < iters; ++t) {
        const int cur = t & 1, nxt = cur ^ 1;
        __syncthreads();            // vmcnt drain: tile t present; buf[nxt] free

        if (t + 1 < iters) {        // 1-ahead DMA overlaps this iter's compute
            __builtin_amdgcn_global_load_lds((gas_t)(const void*)(ga + (t + 1) * 32),
                                             (las_t)(void*)&As[nxt][tid * 8], 16, 0, 0);
            __builtin_amdgcn_global_load_lds((gas_t)(const void*)(gb + (t + 1) * 32),
                                             (las_t)(void*)&Bs[nxt][tid * 8], 16, 0, 0);
        }

        short8x a0 = *(short8x*)&As[cur][(q * 64 + wm +      l15) * 8];
        short8x a1 = *(short8x*)&As[cur][(q * 64 + wm + 16 + l15) * 8];
        short8x b0 = *(short8x*)&Bs[cur][(q * 64 + wn +      l15) * 8];
        short8x b1 = *(short8x*)&Bs[cur][(q * 64 + wn + 16 + l15) * 8];
        acc00 = __builtin_amdgcn_mfma_f32_16x16x32_bf16(a0, b0, acc00, 0, 0, 0);
        acc01 = __builtin_amdgcn_mfma_f32_16x16x32_bf16(a0, b1, acc01, 0, 0, 0);
        acc10 = __builtin_amdgcn_mfma_f32_16x16x32_bf16(a1, b0, acc10, 0, 0, 0);
        acc11 = __builtin_amdgcn_mfma_f32_16x16x32_bf16(a1, b1, acc11, 0, 0, 0);
    }

    float* Cz = Cpart + (size_t)blockIdx.z * M * LDC;
    #pragma unroll
    for (int r = 0; r < 4; ++r) {
        const int rr = m0 + wm + q * 4 + r;
        const int cc = n0 + wn + l15;
        Cz[(size_t)rr * LDC + cc]             = acc00[r];
        Cz[(size_t)rr * LDC + cc + 16]        = acc01[r];
        Cz[(size_t)(rr + 16) * LDC + cc]      = acc10[r];
        Cz[(size_t)(rr + 16) * LDC + cc + 16] = acc11[r];
    }
}

// ---------------------------------------------------------------------------
// Hb = bf16(relu(sum_z Hpart[z] + b1)), 4 elems/thread. Grid 1024.
// ---------------------------------------------------------------------------
__global__ __launch_bounds__(256) void reduce_h_kernel(
    const float* __restrict__ Hpart, const float* __restrict__ b1,
    unsigned short* __restrict__ Hb)
{
    const int i = (blockIdx.x * 256 + threadIdx.x) * 4;
    const int col = i & (HIDD - 1);
    float4 s = *(const float4*)&b1[col];
    #pragma unroll
    for (int z = 0; z < G1_SPLIT; ++z) {
        float4 p = *(const float4*)&Hpart[(size_t)z * B_SZ * HIDD + i];
        s.x += p.x; s.y += p.y; s.z += p.z; s.w += p.w;
    }
    ushort4x o;
    o[0] = f2bf(fmaxf(s.x, 0.f));
    o[1] = f2bf(fmaxf(s.y, 0.f));
    o[2] = f2bf(fmaxf(s.z, 0.f));
    o[3] = f2bf(fmaxf(s.w, 0.f));
    *(ushort4x*)&Hb[i] = o;
}

// ---------------------------------------------------------------------------
// E[m][n] = sum_z Epart[z][m][NPAD..] + b2[n], n < 300. Grid 600.
// ---------------------------------------------------------------------------
__global__ __launch_bounds__(256) void reduce_e_kernel(
    const float* __restrict__ Epart, const float* __restrict__ b2,
    float* __restrict__ E)
{
    const int gid = blockIdx.x * 256 + threadIdx.x;
    if (gid >= B_SZ * EMBD) return;
    const int m = gid / EMBD, n = gid - m * EMBD;
    float v = b2[n];
    #pragma unroll
    for (int z = 0; z < G2_SPLIT; ++z)
        v += Epart[(size_t)z * B_SZ * NPAD + m * NPAD + n];
    E[gid] = v;
}

// ---------------------------------------------------------------------------
// Scores partials: part[z][b][n] = sum_{d in quarter z} relu(E[b,d]-G[n,d])^2.
// Tile 32 b x 64 n, 128 threads, thread = 4 rows x 4 labels (g-reuse 4).
// E read from GLOBAL (16-lane broadcast, L1/L2-hit) -> only G staged in LDS.
// Grid (32, 16, SD_SPLIT) = 2048 blocks -> 8 blocks/CU, 16 waves/CU.
// ---------------------------------------------------------------------------
__global__ __launch_bounds__(128) void scores_part_kernel(
    const float* __restrict__ E, const float* __restrict__ G,
    float* __restrict__ part)
{
    __shared__ float Gs[64][44];             // 11.3 KB, chunk = 40 dims

    const int tid = threadIdx.x;
    const int tx = tid & 15, ty = tid >> 4;  // ty 0..7
    const int n0 = blockIdx.x * 64, b0 = blockIdx.y * 32;
    const int dbase = blockIdx.z * (NPAD / SD_SPLIT);   // 80-dim quarter

    float acc[4][4] = {};

    for (int dc = 0; dc < NPAD / SD_SPLIT; dc += 40) {
        const int d0 = dbase + dc;
        __syncthreads();                     // prev-chunk readers done
        // stage G: 64 rows x 10 float4 slots = 640 -> 5 per thread
        #pragma unroll
        for (int i = 0; i < 5; ++i) {
            const int s = tid + 128 * i;
            const int row = s / 10, qd = (s - row * 10) * 4;
            const int d = d0 + qd;
            const int n = n0 + row;
            float4 v = {0.f, 0.f, 0.f, 0.f};
            if (n < NLAB && d < EMBD) v = *(const float4*)&G[(size_t)n * EMBD + d];
            *(float4*)&Gs[row][qd] = v;
        }
        __syncthreads();

        #pragma unroll 2
        for (int d = 0; d < 40; d += 4) {
            const int dd = d0 + d;
            float4 e[4];
            if (dd < EMBD) {
                #pragma unroll
                for (int r = 0; r < 4; ++r)
                    e[r] = *(const float4*)&E[(size_t)(b0 + ty * 4 + r) * EMBD + dd];
            } else {
                #pragma unroll
                for (int r = 0; r < 4; ++r) e[r] = make_float4(0.f, 0.f, 0.f, 0.f);
            }
            #pragma unroll
            for (int c = 0; c < 4; ++c) {
                float4 g = *(float4*)&Gs[tx + 16 * c][d];
                #pragma unroll
                for (int r = 0; r < 4; ++r) {
                    float t;
                    t = fmaxf(e[r].x - g.x, 0.f); acc[r][c] += t * t;
                    t = fmaxf(e[r].y - g.y, 0.f); acc[r][c] += t * t;
                    t = fmaxf(e[r].z - g.z, 0.f); acc[r][c] += t * t;
                    t = fmaxf(e[r].w - g.w, 0.f); acc[r][c] += t * t;
                }
            }
        }
    }

    float* pz = part + (size_t)blockIdx.z * B_SZ * NLAB;
    #pragma unroll
    for (int r = 0; r < 4; ++r) {
        const int b = b0 + ty * 4 + r;
        #pragma unroll
        for (int c = 0; c < 4; ++c) {
            const int n = n0 + tx + 16 * c;
            if (n < NLAB) pz[(size_t)b * NLAB + n] = acc[r][c];
        }
    }
}

// ---------------------------------------------------------------------------
// scores[i] = -(part[0][i]+part[1][i]+part[2][i]+part[3][i]). Grid 1000.
// ---------------------------------------------------------------------------
__global__ __launch_bounds__(256) void scores_combine_kernel(
    const float* __restrict__ part, float* __restrict__ scores)
{
    const int i = (blockIdx.x * 256 + threadIdx.x) * 4;
    float4 s = {0.f, 0.f, 0.f, 0.f};
    #pragma unroll
    for (int z = 0; z < SD_SPLIT; ++z) {
        float4 p = *(const float4*)&part[(size_t)z * B_SZ * NLAB + i];
        s.x += p.x; s.y += p.y; s.z += p.z; s.w += p.w;
    }
    float4 o = make_float4(-s.x, -s.y, -s.z, -s.w);
    *(float4*)&scores[i] = o;
}

// ---------------------------------------------------------------------------
extern "C" void kernel_launch(void* const* d_in, const int* in_sizes, int n_in,
                              void* d_out, int out_size, void* d_ws, size_t ws_size,
                              hipStream_t stream)
{
    const float* vfs = (const float*)d_in[0];   // [512,4096]
    const float* W1  = (const float*)d_in[1];   // [4096,2048]
    const float* b1  = (const float*)d_in[2];   // [2048]
    const float* W2  = (const float*)d_in[3];   // [2048,300]
    const float* b2  = (const float*)d_in[4];   // [300]
    const float* G   = (const float*)d_in[5];   // [2000,300]

    float* out    = (float*)d_out;
    float* scores = out;                        // [512*2000]
    float* E      = out + (size_t)B_SZ * NLAB;  // [512*300]

    // workspace layout (bytes): total ~46.4 MB (proven to fit)
    char* ws = (char*)d_ws;
    unsigned short* Xb  = (unsigned short*)(ws);             //  4 MB   [512][4096]
    unsigned short* W1T = (unsigned short*)(ws + 4194304);   // 16 MB   [2048][4096]
    unsigned short* W2T = (unsigned short*)(ws + 20971520);  // 1.25 MB [320][2048]
    unsigned short* Hb  = (unsigned short*)(ws + 22282240);  //  2 MB   [512][2048]
    float*          Hpart = (float*)(ws + 24379392);         // 16 MB   [4][512][2048]
    float*          Epart = (float*)(ws + 41156608);         // 5.25 MB [8][512][320]
    // scores partials REUSE the Hpart region (dead after reduce_h):
    // 4 x 512 x 2000 x 4 B = 16.38 MB <= 16.78 MB slot.
    float*          Spart = (float*)(ws + 24379392);

    prep_kernel<<<3232, 256, 0, stream>>>(vfs, Xb, W1, W1T, W2, W2T);

    // GEMM1: [512,2048] = Xb[512,4096] @ W1T^T, split-K 4 -> 1024 blocks
    gemm_bf16_kernel<VFD, VFD, HIDD, VFD / G1_SPLIT>
        <<<dim3(32, 8, G1_SPLIT), 256, 0, stream>>>(Xb, W1T, Hpart, B_SZ);
    reduce_h_kernel<<<1024, 256, 0, stream>>>(Hpart, b1, Hb);

    // GEMM2: [512,320] = Hb[512,2048] @ W2T^T, split-K 8 -> 320 blocks
    gemm_bf16_kernel<HIDD, HIDD, NPAD, HIDD / G2_SPLIT>
        <<<dim3(5, 8, G2_SPLIT), 256, 0, stream>>>(Hb, W2T, Epart, B_SZ);
    reduce_e_kernel<<<600, 256, 0, stream>>>(Epart, b2, E);

    scores_part_kernel<<<dim3(32, 16, SD_SPLIT), 128, 0, stream>>>(E, G, Spart);
    scores_combine_kernel<<<1000, 256, 0, stream>>>(Spart, scores);
}

// Round 7
// 174.548 us; speedup vs baseline: 1.0211x; 1.0211x over previous
//
#include <hip/hip_runtime.h>

#define B_SZ   512
#define VFD    4096
#define HIDD   2048
#define EMBD   300
#define NLAB   2000
#define NPAD   320

#define G1_SPLIT 4          // gemm1 k-chunks: K=4096 -> 1024 each
#define G2_SPLIT 8          // gemm2 k-chunks: K=2048 -> 256 each, 320 blocks
#define SD_SPLIT 4          // scores d-quarters: 320 -> 80 dims each

typedef __attribute__((ext_vector_type(8))) short short8x;
typedef __attribute__((ext_vector_type(4))) float f32x4;
typedef __attribute__((ext_vector_type(8))) unsigned short ushort8;
typedef __attribute__((ext_vector_type(4))) unsigned short ushort4x;

typedef const __attribute__((address_space(1))) unsigned int* gas_t;
typedef __attribute__((address_space(3))) unsigned int* las_t;

__device__ inline unsigned short f2bf(float x) {
    unsigned u = __float_as_uint(x);
    u += 0x7FFF + ((u >> 16) & 1);          // round-to-nearest-even
    return (unsigned short)(u >> 16);
}

// ---------------------------------------------------------------------------
// Fused prep (grid-range dispatch):
//   [0,1024):      Xb = bf16(relu(vfs))
//   [1024,3072):   W1T[n][k] = bf16(W1[k][n])
//   [3072,3232):   W2T[n][k] = bf16(W2[k][n]), n>=300 zero-padded
// ---------------------------------------------------------------------------
__global__ __launch_bounds__(256) void prep_kernel(
    const float* __restrict__ vfs, unsigned short* __restrict__ Xb,
    const float* __restrict__ W1, unsigned short* __restrict__ W1T,
    const float* __restrict__ W2, unsigned short* __restrict__ W2T)
{
    __shared__ float tile[64][65];
    const int tid = threadIdx.x;
    const int blk = blockIdx.x;

    if (blk < 1024) {
        const int i = (blk * 256 + tid) * 8;
        float4 a = *(const float4*)&vfs[i];
        float4 b = *(const float4*)&vfs[i + 4];
        ushort8 o;
        o[0] = f2bf(fmaxf(a.x, 0.f)); o[1] = f2bf(fmaxf(a.y, 0.f));
        o[2] = f2bf(fmaxf(a.z, 0.f)); o[3] = f2bf(fmaxf(a.w, 0.f));
        o[4] = f2bf(fmaxf(b.x, 0.f)); o[5] = f2bf(fmaxf(b.y, 0.f));
        o[6] = f2bf(fmaxf(b.z, 0.f)); o[7] = f2bf(fmaxf(b.w, 0.f));
        *(ushort8*)&Xb[i] = o;
        return;
    }

    const float* in; unsigned short* out; int N, ldK, bx, by;
    if (blk < 3072) {                       // W1: K=4096, N=2048, grid (32,64)
        const int b = blk - 1024;
        in = W1; out = W1T; N = HIDD; ldK = VFD; bx = b & 31; by = b >> 5;
    } else {                                // W2: K=2048, N=300->320, grid (5,32)
        const int b = blk - 3072;
        in = W2; out = W2T; N = EMBD; ldK = HIDD; bx = b % 5; by = b / 5;
    }
    const int n0 = bx * 64, k0 = by * 64;

    #pragma unroll
    for (int i = 0; i < 4; ++i) {
        const int s = tid + 256 * i;
        const int kr = s >> 4, nc = (s & 15) * 4;
        float4 v = {0.f, 0.f, 0.f, 0.f};
        if (n0 + nc < N) v = *(const float4*)&in[(size_t)(k0 + kr) * N + n0 + nc];
        tile[kr][nc + 0] = v.x; tile[kr][nc + 1] = v.y;
        tile[kr][nc + 2] = v.z; tile[kr][nc + 3] = v.w;
    }
    __syncthreads();

    const int row = tid >> 2, kq = (tid & 3) * 16;
    ushort8 o0, o1;
    #pragma unroll
    for (int j = 0; j < 8; ++j) o0[j] = f2bf(tile[kq + j][row]);
    #pragma unroll
    for (int j = 0; j < 8; ++j) o1[j] = f2bf(tile[kq + 8 + j][row]);
    const size_t off = (size_t)(n0 + row) * ldK + k0 + kq;
    *(ushort8*)&out[off]     = o0;
    *(ushort8*)&out[off + 8] = o1;
}

// ---------------------------------------------------------------------------
// GEMM1: Hpart[z][512][2048] = Xb[512,4096] @ W1T[2048,4096]^T, k-chunk z.
// Block 64m x 128n, 4 waves, wave = 32m x 64n (2 A-frags x 4 B-frags ->
// 6 ds_read_b128 : 8 MFMA, 25% less LDS traffic per FLOP than 32x32).
// Double-buffered global_load_lds, one barrier/iter. Grid (16,8,4).
// ---------------------------------------------------------------------------
__global__ __launch_bounds__(256) void gemm1_kernel(
    const unsigned short* __restrict__ A,
    const unsigned short* __restrict__ Bt,
    float* __restrict__ Cpart)
{
    __shared__ unsigned short As[2][2048];   // 64 rows x 32 k  (4 KB)
    __shared__ unsigned short Bs[2][4096];   // 128 rows x 32 k (8 KB)

    const int tid = threadIdx.x;
    const int m0 = blockIdx.y * 64, n0 = blockIdx.x * 128;
    const int kbase = blockIdx.z * (VFD / G1_SPLIT);     // 1024-chunk

    // A staging: slot = (oct 0..3)*64 + row -> tid*16B
    const unsigned short* ga = A + (size_t)(m0 + (tid & 63)) * VFD + kbase + (tid >> 6) * 8;
    // B staging: 512 slots, slot s = (oct)*128 + row; s0 = tid, s1 = tid+256
    const int brow = tid & 127, boct = tid >> 7;         // oct 0..1
    const unsigned short* gb0 = Bt + (size_t)(n0 + brow) * VFD + kbase + boct * 8;
    const unsigned short* gb1 = gb0 + 16;                // octs 2..3

    const int lane = tid & 63;
    const int wave = tid >> 6;
    const int wm = (wave & 1) * 32;
    const int wn = (wave >> 1) * 64;
    const int q = lane >> 4, l15 = lane & 15;

    f32x4 acc[2][4];
    #pragma unroll
    for (int r = 0; r < 2; ++r)
        #pragma unroll
        for (int c = 0; c < 4; ++c) acc[r][c] = (f32x4){0.f,0.f,0.f,0.f};

    __builtin_amdgcn_global_load_lds((gas_t)(const void*)ga,
                                     (las_t)(void*)&As[0][tid * 8], 16, 0, 0);
    __builtin_amdgcn_global_load_lds((gas_t)(const void*)gb0,
                                     (las_t)(void*)&Bs[0][tid * 8], 16, 0, 0);
    __builtin_amdgcn_global_load_lds((gas_t)(const void*)gb1,
                                     (las_t)(void*)&Bs[0][(tid + 256) * 8], 16, 0, 0);

    const int iters = (VFD / G1_SPLIT) / 32;             // 32
    for (int t = 0; t < iters; ++t) {
        const int cur = t & 1, nxt = cur ^ 1;
        __syncthreads();            // vmcnt drain: tile t present; buf[nxt] free

        if (t + 1 < iters) {
            const int ko = (t + 1) * 32;
            __builtin_amdgcn_global_load_lds((gas_t)(const void*)(ga + ko),
                                             (las_t)(void*)&As[nxt][tid * 8], 16, 0, 0);
            __builtin_amdgcn_global_load_lds((gas_t)(const void*)(gb0 + ko),
                                             (las_t)(void*)&Bs[nxt][tid * 8], 16, 0, 0);
            __builtin_amdgcn_global_load_lds((gas_t)(const void*)(gb1 + ko),
                                             (las_t)(void*)&Bs[nxt][(tid + 256) * 8], 16, 0, 0);
        }

        short8x a0 = *(short8x*)&As[cur][(q * 64 + wm +      l15) * 8];
        short8x a1 = *(short8x*)&As[cur][(q * 64 + wm + 16 + l15) * 8];
        #pragma unroll
        for (int c = 0; c < 4; ++c) {
            short8x b = *(short8x*)&Bs[cur][(q * 128 + wn + c * 16 + l15) * 8];
            acc[0][c] = __builtin_amdgcn_mfma_f32_16x16x32_bf16(a0, b, acc[0][c], 0, 0, 0);
            acc[1][c] = __builtin_amdgcn_mfma_f32_16x16x32_bf16(a1, b, acc[1][c], 0, 0, 0);
        }
    }

    float* Cz = Cpart + (size_t)blockIdx.z * B_SZ * HIDD;
    #pragma unroll
    for (int r = 0; r < 2; ++r) {
        #pragma unroll
        for (int g = 0; g < 4; ++g) {
            const int rr = m0 + wm + r * 16 + q * 4 + g;
            #pragma unroll
            for (int c = 0; c < 4; ++c)
                Cz[(size_t)rr * HIDD + n0 + wn + c * 16 + l15] = acc[r][c][g];
        }
    }
}

// ---------------------------------------------------------------------------
// gemm2 (unchanged r5 structure): Epart[z] = Hb @ W2T^T over k-chunk z.
// BM=BN=64, 4 waves of 32x32.
// ---------------------------------------------------------------------------
template<int LDA, int LDB, int LDC, int KCHUNK>
__global__ __launch_bounds__(256) void gemm_bf16_kernel(
    const unsigned short* __restrict__ A,
    const unsigned short* __restrict__ Bt,
    float* __restrict__ Cpart, int M)
{
    __shared__ unsigned short As[2][2048];
    __shared__ unsigned short Bs[2][2048];

    const int tid = threadIdx.x;
    const int m0 = blockIdx.y * 64, n0 = blockIdx.x * 64;
    const int kbase = blockIdx.z * KCHUNK;

    const unsigned short* ga = A  + (size_t)(m0 + (tid & 63)) * LDA + kbase + (tid >> 6) * 8;
    const unsigned short* gb = Bt + (size_t)(n0 + (tid & 63)) * LDB + kbase + (tid >> 6) * 8;

    const int lane = tid & 63;
    const int wave = tid >> 6;
    const int wm = (wave & 1) * 32;
    const int wn = (wave >> 1) * 32;
    const int q = lane >> 4, l15 = lane & 15;

    f32x4 acc00 = {0.f,0.f,0.f,0.f}, acc01 = {0.f,0.f,0.f,0.f};
    f32x4 acc10 = {0.f,0.f,0.f,0.f}, acc11 = {0.f,0.f,0.f,0.f};

    __builtin_amdgcn_global_load_lds((gas_t)(const void*)ga,
                                     (las_t)(void*)&As[0][tid * 8], 16, 0, 0);
    __builtin_amdgcn_global_load_lds((gas_t)(const void*)gb,
                                     (las_t)(void*)&Bs[0][tid * 8], 16, 0, 0);

    const int iters = KCHUNK / 32;
    for (int t = 0; t < iters; ++t) {
        const int cur = t & 1, nxt = cur ^ 1;
        __syncthreads();

        if (t + 1 < iters) {
            __builtin_amdgcn_global_load_lds((gas_t)(const void*)(ga + (t + 1) * 32),
                                             (las_t)(void*)&As[nxt][tid * 8], 16, 0, 0);
            __builtin_amdgcn_global_load_lds((gas_t)(const void*)(gb + (t + 1) * 32),
                                             (las_t)(void*)&Bs[nxt][tid * 8], 16, 0, 0);
        }

        short8x a0 = *(short8x*)&As[cur][(q * 64 + wm +      l15) * 8];
        short8x a1 = *(short8x*)&As[cur][(q * 64 + wm + 16 + l15) * 8];
        short8x b0 = *(short8x*)&Bs[cur][(q * 64 + wn +      l15) * 8];
        short8x b1 = *(short8x*)&Bs[cur][(q * 64 + wn + 16 + l15) * 8];
        acc00 = __builtin_amdgcn_mfma_f32_16x16x32_bf16(a0, b0, acc00, 0, 0, 0);
        acc01 = __builtin_amdgcn_mfma_f32_16x16x32_bf16(a0, b1, acc01, 0, 0, 0);
        acc10 = __builtin_amdgcn_mfma_f32_16x16x32_bf16(a1, b0, acc10, 0, 0, 0);
        acc11 = __builtin_amdgcn_mfma_f32_16x16x32_bf16(a1, b1, acc11, 0, 0, 0);
    }

    float* Cz = Cpart + (size_t)blockIdx.z * M * LDC;
    #pragma unroll
    for (int r = 0; r < 4; ++r) {
        const int rr = m0 + wm + q * 4 + r;
        const int cc = n0 + wn + l15;
        Cz[(size_t)rr * LDC + cc]             = acc00[r];
        Cz[(size_t)rr * LDC + cc + 16]        = acc01[r];
        Cz[(size_t)(rr + 16) * LDC + cc]      = acc10[r];
        Cz[(size_t)(rr + 16) * LDC + cc + 16] = acc11[r];
    }
}

// ---------------------------------------------------------------------------
// Hb = bf16(relu(sum_z Hpart[z] + b1)), 4 elems/thread. Grid 1024.
// ---------------------------------------------------------------------------
__global__ __launch_bounds__(256) void reduce_h_kernel(
    const float* __restrict__ Hpart, const float* __restrict__ b1,
    unsigned short* __restrict__ Hb)
{
    const int i = (blockIdx.x * 256 + threadIdx.x) * 4;
    const int col = i & (HIDD - 1);
    float4 s = *(const float4*)&b1[col];
    #pragma unroll
    for (int z = 0; z < G1_SPLIT; ++z) {
        float4 p = *(const float4*)&Hpart[(size_t)z * B_SZ * HIDD + i];
        s.x += p.x; s.y += p.y; s.z += p.z; s.w += p.w;
    }
    ushort4x o;
    o[0] = f2bf(fmaxf(s.x, 0.f));
    o[1] = f2bf(fmaxf(s.y, 0.f));
    o[2] = f2bf(fmaxf(s.z, 0.f));
    o[3] = f2bf(fmaxf(s.w, 0.f));
    *(ushort4x*)&Hb[i] = o;
}

// ---------------------------------------------------------------------------
// blocks [0,600): E[m][n] = sum_z Epart[z][m][n..] + b2[n]
// blocks [600,1624): scores <- 0 (accumulation target for scores_part)
// ---------------------------------------------------------------------------
__global__ __launch_bounds__(256) void reduce_e_zero_kernel(
    const float* __restrict__ Epart, const float* __restrict__ b2,
    float* __restrict__ E, float* __restrict__ scores)
{
    const int blk = blockIdx.x;
    if (blk < 600) {
        const int gid = blk * 256 + threadIdx.x;
        if (gid >= B_SZ * EMBD) return;
        const int m = gid / EMBD, n = gid - m * EMBD;
        float v = b2[n];
        #pragma unroll
        for (int z = 0; z < G2_SPLIT; ++z)
            v += Epart[(size_t)z * B_SZ * NPAD + m * NPAD + n];
        E[gid] = v;
    } else {
        const int i = ((blk - 600) * 256 + threadIdx.x) * 4;
        if (i < B_SZ * NLAB) {
            float4 z = {0.f, 0.f, 0.f, 0.f};
            *(float4*)&scores[i] = z;
        }
    }
}

// ---------------------------------------------------------------------------
// Scores partials: atomicAdd(scores[b][n], -sum_{d in quarter} relu(E-G)^2).
// Tile 32 b x 64 n, 128 threads, thread = 4 rows x 4 labels.
// E from global (lane-broadcast, L2-hit); G staged in LDS.
// Grid (32, 16, SD_SPLIT) = 2048 blocks.
// ---------------------------------------------------------------------------
__global__ __launch_bounds__(128) void scores_part_kernel(
    const float* __restrict__ E, const float* __restrict__ G,
    float* __restrict__ scores)
{
    __shared__ float Gs[64][44];             // chunk = 40 dims

    const int tid = threadIdx.x;
    const int tx = tid & 15, ty = tid >> 4;  // ty 0..7
    const int n0 = blockIdx.x * 64, b0 = blockIdx.y * 32;
    const int dbase = blockIdx.z * (NPAD / SD_SPLIT);   // 80-dim quarter

    float acc[4][4] = {};

    for (int dc = 0; dc < NPAD / SD_SPLIT; dc += 40) {
        const int d0 = dbase + dc;
        __syncthreads();
        #pragma unroll
        for (int i = 0; i < 5; ++i) {
            const int s = tid + 128 * i;
            const int row = s / 10, qd = (s - row * 10) * 4;
            const int d = d0 + qd;
            const int n = n0 + row;
            float4 v = {0.f, 0.f, 0.f, 0.f};
            if (n < NLAB && d < EMBD) v = *(const float4*)&G[(size_t)n * EMBD + d];
            *(float4*)&Gs[row][qd] = v;
        }
        __syncthreads();

        #pragma unroll 2
        for (int d = 0; d < 40; d += 4) {
            const int dd = d0 + d;
            float4 e[4];
            if (dd < EMBD) {
                #pragma unroll
                for (int r = 0; r < 4; ++r)
                    e[r] = *(const float4*)&E[(size_t)(b0 + ty * 4 + r) * EMBD + dd];
            } else {
                #pragma unroll
                for (int r = 0; r < 4; ++r) e[r] = make_float4(0.f, 0.f, 0.f, 0.f);
            }
            #pragma unroll
            for (int c = 0; c < 4; ++c) {
                float4 g = *(float4*)&Gs[tx + 16 * c][d];
                #pragma unroll
                for (int r = 0; r < 4; ++r) {
                    float t;
                    t = fmaxf(e[r].x - g.x, 0.f); acc[r][c] += t * t;
                    t = fmaxf(e[r].y - g.y, 0.f); acc[r][c] += t * t;
                    t = fmaxf(e[r].z - g.z, 0.f); acc[r][c] += t * t;
                    t = fmaxf(e[r].w - g.w, 0.f); acc[r][c] += t * t;
                }
            }
        }
    }

    #pragma unroll
    for (int r = 0; r < 4; ++r) {
        const int b = b0 + ty * 4 + r;
        #pragma unroll
        for (int c = 0; c < 4; ++c) {
            const int n = n0 + tx + 16 * c;
            if (n < NLAB) atomicAdd(&scores[(size_t)b * NLAB + n], -acc[r][c]);
        }
    }
}

// ---------------------------------------------------------------------------
extern "C" void kernel_launch(void* const* d_in, const int* in_sizes, int n_in,
                              void* d_out, int out_size, void* d_ws, size_t ws_size,
                              hipStream_t stream)
{
    const float* vfs = (const float*)d_in[0];   // [512,4096]
    const float* W1  = (const float*)d_in[1];   // [4096,2048]
    const float* b1  = (const float*)d_in[2];   // [2048]
    const float* W2  = (const float*)d_in[3];   // [2048,300]
    const float* b2  = (const float*)d_in[4];   // [300]
    const float* G   = (const float*)d_in[5];   // [2000,300]

    float* out    = (float*)d_out;
    float* scores = out;                        // [512*2000]
    float* E      = out + (size_t)B_SZ * NLAB;  // [512*300]

    // workspace layout (bytes): ~46.4 MB used (ws is ~268 MB per fill counter)
    char* ws = (char*)d_ws;
    unsigned short* Xb  = (unsigned short*)(ws);             //  4 MB   [512][4096]
    unsigned short* W1T = (unsigned short*)(ws + 4194304);   // 16 MB   [2048][4096]
    unsigned short* W2T = (unsigned short*)(ws + 20971520);  // 1.25 MB [320][2048]
    unsigned short* Hb  = (unsigned short*)(ws + 22282240);  //  2 MB   [512][2048]
    float*          Hpart = (float*)(ws + 24379392);         // 16 MB   [4][512][2048]
    float*          Epart = (float*)(ws + 41156608);         // 5.25 MB [8][512][320]

    prep_kernel<<<3232, 256, 0, stream>>>(vfs, Xb, W1, W1T, W2, W2T);

    // GEMM1: 64x128 tile, grid (16,8,4) = 512 blocks
    gemm1_kernel<<<dim3(16, 8, G1_SPLIT), 256, 0, stream>>>(Xb, W1T, Hpart);
    reduce_h_kernel<<<1024, 256, 0, stream>>>(Hpart, b1, Hb);

    // GEMM2: [512,320] = Hb[512,2048] @ W2T^T, split-K 8 -> 320 blocks
    gemm_bf16_kernel<HIDD, HIDD, NPAD, HIDD / G2_SPLIT>
        <<<dim3(5, 8, G2_SPLIT), 256, 0, stream>>>(Hb, W2T, Epart, B_SZ);
    reduce_e_zero_kernel<<<1624, 256, 0, stream>>>(Epart, b2, E, scores);

    scores_part_kernel<<<dim3(32, 16, SD_SPLIT), 128, 0, stream>>>(E, G, scores);
}

// Round 8
// 170.177 us; speedup vs baseline: 1.0473x; 1.0257x over previous
//
#include <hip/hip_runtime.h>

#define B_SZ   512
#define VFD    4096
#define HIDD   2048
#define EMBD   300
#define NLAB   2000
#define NPAD   320

#define G1_SPLIT 4          // gemm1 k-chunks: K=4096 -> 1024 each
#define G2_SPLIT 8          // gemm2 k-chunks: K=2048 -> 256 each
#define SD_SPLIT 4          // scores d-quarters: 320 -> 80 dims each

typedef __attribute__((ext_vector_type(8))) short short8x;
typedef __attribute__((ext_vector_type(4))) float f32x4;
typedef __attribute__((ext_vector_type(8))) unsigned short ushort8;
typedef __attribute__((ext_vector_type(4))) unsigned short ushort4x;

typedef const __attribute__((address_space(1))) unsigned int* gas_t;
typedef __attribute__((address_space(3))) unsigned int* las_t;

__device__ inline unsigned short f2bf(float x) {
    unsigned u = __float_as_uint(x);
    u += 0x7FFF + ((u >> 16) & 1);          // round-to-nearest-even
    return (unsigned short)(u >> 16);
}

// ---------------------------------------------------------------------------
// Fused prep (grid-range dispatch):
//   [0,1024):       Xb = bf16(relu(vfs))
//   [1024,3072):    W1T[n][k] = bf16(W1[k][n])  (pair-packed transpose v2)
//   [3072,3232):    W2T[n][k] = bf16(W2[k][n]), n>=300 zero-padded
//   [3232,4256):    scores <- 0 (accum target for scores_part atomics)
// Transpose v2: convert+pack (k,k+1) bf16 pairs into u32 BEFORE LDS ->
// 8 ds_write_b32 + 4 ds_read_b64 per thread (vs 8 f32 wr + 32 scalar rd).
// ---------------------------------------------------------------------------
__global__ __launch_bounds__(256) void prep_kernel(
    const float* __restrict__ vfs, unsigned short* __restrict__ Xb,
    const float* __restrict__ W1, unsigned short* __restrict__ W1T,
    const float* __restrict__ W2, unsigned short* __restrict__ W2T,
    float* __restrict__ scores)
{
    __shared__ unsigned int Lds[64][34];    // [n][kpair], stride 34 (b64-aligned)
    const int tid = threadIdx.x;
    const int blk = blockIdx.x;

    if (blk < 1024) {                       // Xb = bf16(relu(vfs))
        const int i = (blk * 256 + tid) * 8;
        float4 a = *(const float4*)&vfs[i];
        float4 b = *(const float4*)&vfs[i + 4];
        ushort8 o;
        o[0] = f2bf(fmaxf(a.x, 0.f)); o[1] = f2bf(fmaxf(a.y, 0.f));
        o[2] = f2bf(fmaxf(a.z, 0.f)); o[3] = f2bf(fmaxf(a.w, 0.f));
        o[4] = f2bf(fmaxf(b.x, 0.f)); o[5] = f2bf(fmaxf(b.y, 0.f));
        o[6] = f2bf(fmaxf(b.z, 0.f)); o[7] = f2bf(fmaxf(b.w, 0.f));
        *(ushort8*)&Xb[i] = o;
        return;
    }
    if (blk >= 3232) {                      // zero scores
        const int i = ((blk - 3232) * 256 + tid) * 4;
        if (i < B_SZ * NLAB) {
            float4 z = {0.f, 0.f, 0.f, 0.f};
            *(float4*)&scores[i] = z;
        }
        return;
    }

    const float* in; unsigned short* out; int N, ldK, bx, by;
    if (blk < 3072) {                       // W1: K=4096, N=2048, tiles (32,64)
        const int b = blk - 1024;
        in = W1; out = W1T; N = HIDD; ldK = VFD; bx = b & 31; by = b >> 5;
    } else {                                // W2: K=2048, N=300->320, tiles (5,32)
        const int b = blk - 3072;
        in = W2; out = W2T; N = EMBD; ldK = HIDD; bx = b % 5; by = b / 5;
    }
    const int n0 = bx * 64, k0 = by * 64;

    // phase 1: 512 slots (kpair 0..31 x nquad 0..15), 2 per thread
    #pragma unroll
    for (int i = 0; i < 2; ++i) {
        const int s = tid + 256 * i;
        const int kp = s >> 4, nq = s & 15;
        const int n = n0 + nq * 4;
        float4 v0 = {0.f,0.f,0.f,0.f}, v1 = {0.f,0.f,0.f,0.f};
        if (n < N) {
            v0 = *(const float4*)&in[(size_t)(k0 + 2 * kp)     * N + n];
            v1 = *(const float4*)&in[(size_t)(k0 + 2 * kp + 1) * N + n];
        }
        Lds[nq*4+0][kp] = (unsigned)f2bf(v0.x) | ((unsigned)f2bf(v1.x) << 16);
        Lds[nq*4+1][kp] = (unsigned)f2bf(v0.y) | ((unsigned)f2bf(v1.y) << 16);
        Lds[nq*4+2][kp] = (unsigned)f2bf(v0.z) | ((unsigned)f2bf(v1.z) << 16);
        Lds[nq*4+3][kp] = (unsigned)f2bf(v0.w) | ((unsigned)f2bf(v1.w) << 16);
    }
    __syncthreads();

    // phase 2: 512 chunks (n 0..63 x k-octet 0..7), 2 per thread
    #pragma unroll
    for (int i = 0; i < 2; ++i) {
        const int c = tid + 256 * i;
        const int n = c >> 3, oct = c & 7;
        uint2 lo = *(uint2*)&Lds[n][oct * 4];
        uint2 hi = *(uint2*)&Lds[n][oct * 4 + 2];
        uint4 v = make_uint4(lo.x, lo.y, hi.x, hi.y);
        *(uint4*)&out[(size_t)(n0 + n) * ldK + k0 + oct * 8] = v;
    }
}

// ---------------------------------------------------------------------------
// GEMM1: Hpart[z][512][2048] = Xb @ W1T^T over k-chunk z.
// Block 64m x 128n, BK=64 (16 iters, half the barriers of BK=32).
// 4 waves, wave = 32m x 64n. LDS dbuf 48 KB. Grid (16,8,4).
// LDS layout [k-octet][row] in 16B units; DMA slots are tid-linear.
// ---------------------------------------------------------------------------
__global__ __launch_bounds__(256) void gemm1_kernel(
    const unsigned short* __restrict__ A,
    const unsigned short* __restrict__ Bt,
    float* __restrict__ Cpart)
{
    __shared__ unsigned short As[2][4096];   // 8 oct x 64 rows  (8 KB each)
    __shared__ unsigned short Bs[2][8192];   // 8 oct x 128 rows (16 KB each)

    const int tid = threadIdx.x;
    const int m0 = blockIdx.y * 64, n0 = blockIdx.x * 128;
    const int kbase = blockIdx.z * (VFD / G1_SPLIT);     // 1024

    const unsigned short* ga = A + (size_t)(m0 + (tid & 63)) * VFD + kbase + (tid >> 6) * 8;
    const unsigned short* gb = Bt + (size_t)(n0 + (tid & 127)) * VFD + kbase + (tid >> 7) * 8;

    const int lane = tid & 63;
    const int wave = tid >> 6;
    const int wm = (wave & 1) * 32;
    const int wn = (wave >> 1) * 64;
    const int q = lane >> 4, l15 = lane & 15;

    f32x4 acc[2][4];
    #pragma unroll
    for (int r = 0; r < 2; ++r)
        #pragma unroll
        for (int c = 0; c < 4; ++c) acc[r][c] = (f32x4){0.f,0.f,0.f,0.f};

    // prefetch tile 0: A 2 DMA (octs tid>>6, +4), B 4 DMA (octs tid>>7, +2,+4,+6)
    #pragma unroll
    for (int i = 0; i < 2; ++i)
        __builtin_amdgcn_global_load_lds((gas_t)(const void*)(ga + i * 32),
                                         (las_t)(void*)&As[0][(tid + 256 * i) * 8], 16, 0, 0);
    #pragma unroll
    for (int i = 0; i < 4; ++i)
        __builtin_amdgcn_global_load_lds((gas_t)(const void*)(gb + i * 16),
                                         (las_t)(void*)&Bs[0][(tid + 256 * i) * 8], 16, 0, 0);

    const int iters = (VFD / G1_SPLIT) / 64;             // 16
    for (int t = 0; t < iters; ++t) {
        const int cur = t & 1, nxt = cur ^ 1;
        __syncthreads();            // vmcnt drain: tile t present; buf[nxt] free

        if (t + 1 < iters) {
            const int ko = (t + 1) * 64;
            #pragma unroll
            for (int i = 0; i < 2; ++i)
                __builtin_amdgcn_global_load_lds((gas_t)(const void*)(ga + ko + i * 32),
                                                 (las_t)(void*)&As[nxt][(tid + 256 * i) * 8], 16, 0, 0);
            #pragma unroll
            for (int i = 0; i < 4; ++i)
                __builtin_amdgcn_global_load_lds((gas_t)(const void*)(gb + ko + i * 16),
                                                 (las_t)(void*)&Bs[nxt][(tid + 256 * i) * 8], 16, 0, 0);
        }

        #pragma unroll
        for (int kk = 0; kk < 2; ++kk) {
            const int oct = kk * 4 + q;
            short8x a0 = *(short8x*)&As[cur][(oct * 64 + wm +      l15) * 8];
            short8x a1 = *(short8x*)&As[cur][(oct * 64 + wm + 16 + l15) * 8];
            #pragma unroll
            for (int c = 0; c < 4; ++c) {
                short8x b = *(short8x*)&Bs[cur][(oct * 128 + wn + c * 16 + l15) * 8];
                acc[0][c] = __builtin_amdgcn_mfma_f32_16x16x32_bf16(a0, b, acc[0][c], 0, 0, 0);
                acc[1][c] = __builtin_amdgcn_mfma_f32_16x16x32_bf16(a1, b, acc[1][c], 0, 0, 0);
            }
        }
    }

    float* Cz = Cpart + (size_t)blockIdx.z * B_SZ * HIDD;
    #pragma unroll
    for (int r = 0; r < 2; ++r) {
        #pragma unroll
        for (int g = 0; g < 4; ++g) {
            const int rr = m0 + wm + r * 16 + q * 4 + g;
            #pragma unroll
            for (int c = 0; c < 4; ++c)
                Cz[(size_t)rr * HIDD + n0 + wn + c * 16 + l15] = acc[r][c][g];
        }
    }
}

// ---------------------------------------------------------------------------
// GEMM2: Epart[z] = Hb @ W2T^T over k-chunk z. BM=BN=64, BK=64 (4 iters).
// 4 waves of 32x32. Grid (5, 8, G2_SPLIT).
// ---------------------------------------------------------------------------
template<int LDA, int LDB, int LDC, int KCHUNK>
__global__ __launch_bounds__(256) void gemm_bf16_kernel(
    const unsigned short* __restrict__ A,
    const unsigned short* __restrict__ Bt,
    float* __restrict__ Cpart, int M)
{
    __shared__ unsigned short As[2][4096];   // 8 oct x 64 rows
    __shared__ unsigned short Bs[2][4096];

    const int tid = threadIdx.x;
    const int m0 = blockIdx.y * 64, n0 = blockIdx.x * 64;
    const int kbase = blockIdx.z * KCHUNK;

    const unsigned short* ga = A  + (size_t)(m0 + (tid & 63)) * LDA + kbase + (tid >> 6) * 8;
    const unsigned short* gb = Bt + (size_t)(n0 + (tid & 63)) * LDB + kbase + (tid >> 6) * 8;

    const int lane = tid & 63;
    const int wave = tid >> 6;
    const int wm = (wave & 1) * 32;
    const int wn = (wave >> 1) * 32;
    const int q = lane >> 4, l15 = lane & 15;

    f32x4 acc00 = {0.f,0.f,0.f,0.f}, acc01 = {0.f,0.f,0.f,0.f};
    f32x4 acc10 = {0.f,0.f,0.f,0.f}, acc11 = {0.f,0.f,0.f,0.f};

    #pragma unroll
    for (int i = 0; i < 2; ++i) {
        __builtin_amdgcn_global_load_lds((gas_t)(const void*)(ga + i * 32),
                                         (las_t)(void*)&As[0][(tid + 256 * i) * 8], 16, 0, 0);
        __builtin_amdgcn_global_load_lds((gas_t)(const void*)(gb + i * 32),
                                         (las_t)(void*)&Bs[0][(tid + 256 * i) * 8], 16, 0, 0);
    }

    const int iters = KCHUNK / 64;
    for (int t = 0; t < iters; ++t) {
        const int cur = t & 1, nxt = cur ^ 1;
        __syncthreads();

        if (t + 1 < iters) {
            const int ko = (t + 1) * 64;
            #pragma unroll
            for (int i = 0; i < 2; ++i) {
                __builtin_amdgcn_global_load_lds((gas_t)(const void*)(ga + ko + i * 32),
                                                 (las_t)(void*)&As[nxt][(tid + 256 * i) * 8], 16, 0, 0);
                __builtin_amdgcn_global_load_lds((gas_t)(const void*)(gb + ko + i * 32),
                                                 (las_t)(void*)&Bs[nxt][(tid + 256 * i) * 8], 16, 0, 0);
            }
        }

        #pragma unroll
        for (int kk = 0; kk < 2; ++kk) {
            const int oct = kk * 4 + q;
            short8x a0 = *(short8x*)&As[cur][(oct * 64 + wm +      l15) * 8];
            short8x a1 = *(short8x*)&As[cur][(oct * 64 + wm + 16 + l15) * 8];
            short8x b0 = *(short8x*)&Bs[cur][(oct * 64 + wn +      l15) * 8];
            short8x b1 = *(short8x*)&Bs[cur][(oct * 64 + wn + 16 + l15) * 8];
            acc00 = __builtin_amdgcn_mfma_f32_16x16x32_bf16(a0, b0, acc00, 0, 0, 0);
            acc01 = __builtin_amdgcn_mfma_f32_16x16x32_bf16(a0, b1, acc01, 0, 0, 0);
            acc10 = __builtin_amdgcn_mfma_f32_16x16x32_bf16(a1, b0, acc10, 0, 0, 0);
            acc11 = __builtin_amdgcn_mfma_f32_16x16x32_bf16(a1, b1, acc11, 0, 0, 0);
        }
    }

    float* Cz = Cpart + (size_t)blockIdx.z * M * LDC;
    #pragma unroll
    for (int r = 0; r < 4; ++r) {
        const int rr = m0 + wm + q * 4 + r;
        const int cc = n0 + wn + l15;
        Cz[(size_t)rr * LDC + cc]             = acc00[r];
        Cz[(size_t)rr * LDC + cc + 16]        = acc01[r];
        Cz[(size_t)(rr + 16) * LDC + cc]      = acc10[r];
        Cz[(size_t)(rr + 16) * LDC + cc + 16] = acc11[r];
    }
}

// ---------------------------------------------------------------------------
// Hb = bf16(relu(sum_z Hpart[z] + b1)), 4 elems/thread. Grid 1024.
// ---------------------------------------------------------------------------
__global__ __launch_bounds__(256) void reduce_h_kernel(
    const float* __restrict__ Hpart, const float* __restrict__ b1,
    unsigned short* __restrict__ Hb)
{
    const int i = (blockIdx.x * 256 + threadIdx.x) * 4;
    const int col = i & (HIDD - 1);
    float4 s = *(const float4*)&b1[col];
    #pragma unroll
    for (int z = 0; z < G1_SPLIT; ++z) {
        float4 p = *(const float4*)&Hpart[(size_t)z * B_SZ * HIDD + i];
        s.x += p.x; s.y += p.y; s.z += p.z; s.w += p.w;
    }
    ushort4x o;
    o[0] = f2bf(fmaxf(s.x, 0.f));
    o[1] = f2bf(fmaxf(s.y, 0.f));
    o[2] = f2bf(fmaxf(s.z, 0.f));
    o[3] = f2bf(fmaxf(s.w, 0.f));
    *(ushort4x*)&Hb[i] = o;
}

// ---------------------------------------------------------------------------
// E[m][n] = sum_z Epart[z][m][n] + b2[n], n < 300. Grid 600.
// ---------------------------------------------------------------------------
__global__ __launch_bounds__(256) void reduce_e_kernel(
    const float* __restrict__ Epart, const float* __restrict__ b2,
    float* __restrict__ E)
{
    const int gid = blockIdx.x * 256 + threadIdx.x;
    if (gid >= B_SZ * EMBD) return;
    const int m = gid / EMBD, n = gid - m * EMBD;
    float v = b2[n];
    #pragma unroll
    for (int z = 0; z < G2_SPLIT; ++z)
        v += Epart[(size_t)z * B_SZ * NPAD + m * NPAD + n];
    E[gid] = v;
}

// ---------------------------------------------------------------------------
// Scores partials: atomicAdd(scores[b][n], -sum_{d in quarter} relu(E-G)^2).
// Tile 32 b x 64 n, 128 threads, thread = 4 rows x 4 labels.
// E from global (lane-broadcast, L2); G staged in LDS.
// Grid (32, 16, SD_SPLIT) = 2048 blocks -> 16 waves/CU.
// ---------------------------------------------------------------------------
__global__ __launch_bounds__(128) void scores_part_kernel(
    const float* __restrict__ E, const float* __restrict__ G,
    float* __restrict__ scores)
{
    __shared__ float Gs[64][44];             // chunk = 40 dims

    const int tid = threadIdx.x;
    const int tx = tid & 15, ty = tid >> 4;  // ty 0..7
    const int n0 = blockIdx.x * 64, b0 = blockIdx.y * 32;
    const int dbase = blockIdx.z * (NPAD / SD_SPLIT);   // 80-dim quarter

    float acc[4][4] = {};

    for (int dc = 0; dc < NPAD / SD_SPLIT; dc += 40) {
        const int d0 = dbase + dc;
        __syncthreads();
        #pragma unroll
        for (int i = 0; i < 5; ++i) {
            const int s = tid + 128 * i;
            const int row = s / 10, qd = (s - row * 10) * 4;
            const int d = d0 + qd;
            const int n = n0 + row;
            float4 v = {0.f, 0.f, 0.f, 0.f};
            if (n < NLAB && d < EMBD) v = *(const float4*)&G[(size_t)n * EMBD + d];
            *(float4*)&Gs[row][qd] = v;
        }
        __syncthreads();

        #pragma unroll 2
        for (int d = 0; d < 40; d += 4) {
            const int dd = d0 + d;
            float4 e[4];
            if (dd < EMBD) {
                #pragma unroll
                for (int r = 0; r < 4; ++r)
                    e[r] = *(const float4*)&E[(size_t)(b0 + ty * 4 + r) * EMBD + dd];
            } else {
                #pragma unroll
                for (int r = 0; r < 4; ++r) e[r] = make_float4(0.f, 0.f, 0.f, 0.f);
            }
            #pragma unroll
            for (int c = 0; c < 4; ++c) {
                float4 g = *(float4*)&Gs[tx + 16 * c][d];
                #pragma unroll
                for (int r = 0; r < 4; ++r) {
                    float t;
                    t = fmaxf(e[r].x - g.x, 0.f); acc[r][c] += t * t;
                    t = fmaxf(e[r].y - g.y, 0.f); acc[r][c] += t * t;
                    t = fmaxf(e[r].z - g.z, 0.f); acc[r][c] += t * t;
                    t = fmaxf(e[r].w - g.w, 0.f); acc[r][c] += t * t;
                }
            }
        }
    }

    #pragma unroll
    for (int r = 0; r < 4; ++r) {
        const int b = b0 + ty * 4 + r;
        #pragma unroll
        for (int c = 0; c < 4; ++c) {
            const int n = n0 + tx + 16 * c;
            if (n < NLAB) atomicAdd(&scores[(size_t)b * NLAB + n], -acc[r][c]);
        }
    }
}

// ---------------------------------------------------------------------------
extern "C" void kernel_launch(void* const* d_in, const int* in_sizes, int n_in,
                              void* d_out, int out_size, void* d_ws, size_t ws_size,
                              hipStream_t stream)
{
    const float* vfs = (const float*)d_in[0];   // [512,4096]
    const float* W1  = (const float*)d_in[1];   // [4096,2048]
    const float* b1  = (const float*)d_in[2];   // [2048]
    const float* W2  = (const float*)d_in[3];   // [2048,300]
    const float* b2  = (const float*)d_in[4];   // [300]
    const float* G   = (const float*)d_in[5];   // [2000,300]

    float* out    = (float*)d_out;
    float* scores = out;                        // [512*2000]
    float* E      = out + (size_t)B_SZ * NLAB;  // [512*300]

    // workspace layout (bytes): ~46.4 MB used
    char* ws = (char*)d_ws;
    unsigned short* Xb  = (unsigned short*)(ws);             //  4 MB   [512][4096]
    unsigned short* W1T = (unsigned short*)(ws + 4194304);   // 16 MB   [2048][4096]
    unsigned short* W2T = (unsigned short*)(ws + 20971520);  // 1.25 MB [320][2048]
    unsigned short* Hb  = (unsigned short*)(ws + 22282240);  //  2 MB   [512][2048]
    float*          Hpart = (float*)(ws + 24379392);         // 16 MB   [4][512][2048]
    float*          Epart = (float*)(ws + 41156608);         // 5.25 MB [8][512][320]

    // prep: Xb conv (1024) + W1T (2048) + W2T (160) + zero scores (1024)
    prep_kernel<<<4256, 256, 0, stream>>>(vfs, Xb, W1, W1T, W2, W2T, scores);

    // GEMM1: 64x128 tile, BK=64, grid (16,8,4) = 512 blocks
    gemm1_kernel<<<dim3(16, 8, G1_SPLIT), 256, 0, stream>>>(Xb, W1T, Hpart);
    reduce_h_kernel<<<1024, 256, 0, stream>>>(Hpart, b1, Hb);

    // GEMM2: [512,320] = Hb[512,2048] @ W2T^T, BK=64, split-K 8 -> 320 blocks
    gemm_bf16_kernel<HIDD, HIDD, NPAD, HIDD / G2_SPLIT>
        <<<dim3(5, 8, G2_SPLIT), 256, 0, stream>>>(Hb, W2T, Epart, B_SZ);
    reduce_e_kernel<<<600, 256, 0, stream>>>(Epart, b2, E);

    scores_part_kernel<<<dim3(32, 16, SD_SPLIT), 128, 0, stream>>>(E, G, scores);
}